// Round 1
// baseline (20.446 us; speedup 1.0000x reference)
//
#include <hip/hip_runtime.h>

// HistByProfMultiChannel: x (16,128,56,56) f32, hist_edges (128,10) f32
// out (16,128,11) f32. One block per (bt,c); 3136 contiguous pixels reduced
// into 11 bins.

#define NE 10
#define NBINS 11
#define HW 3136
#define HW4 784   // HW / 4
#define NCH 128

__global__ __launch_bounds__(256)
void hist_kernel(const float* __restrict__ x,
                 const float* __restrict__ edges,
                 float* __restrict__ out) {
    const int bc  = blockIdx.x;          // bt*NCH + c
    const int c   = bc & (NCH - 1);
    const int tid = threadIdx.x;

    // Edges are block-uniform -> scalar loads, L2 broadcast.
    float e[NE];
    #pragma unroll
    for (int j = 0; j < NE; ++j) e[j] = edges[c * NE + j];

    const float LOG2E = 1.4426950408889634f;

    // Per-bin quadratic coefficients: exp(-0.5*((v-mu)/sig)^2) = exp2(A*v^2 + B*v + C)
    float A[NE], B[NE], Cc[NE];
    {
        // bin 0: mu = e0, sig = (e0-e1)/3 (+1e-6)
        float mu  = e[0];
        float sig = (e[0] - e[1]) * (1.0f / 3.0f) + 1e-6f;
        float k   = -0.5f * LOG2E / (sig * sig);
        A[0] = k; B[0] = -2.0f * k * mu; Cc[0] = k * mu * mu;
    }
    #pragma unroll
    for (int j = 1; j < NE; ++j) {
        float mu  = (e[j - 1] + e[j]) * 0.5f;
        float sig = (e[j - 1] - e[j]) * (1.0f / 3.0f) + 1e-6f;
        float k   = -0.5f * LOG2E / (sig * sig);
        A[j] = k; B[j] = -2.0f * k * mu; Cc[j] = k * mu * mu;
    }
    // sigmoid tail: 1/(1+exp(-20*(v-e9))) = rcp(1 + exp2(sB*v + sC))
    const float sB = -20.0f * LOG2E;
    const float sC =  20.0f * LOG2E * e[NE - 1];

    float acc[NBINS];
    #pragma unroll
    for (int j = 0; j < NBINS; ++j) acc[j] = 0.0f;

    const float4* xp = (const float4*)(x + (size_t)bc * HW);
    for (int i = tid; i < HW4; i += 256) {
        float4 v4 = xp[i];
        float vs[4] = {v4.x, v4.y, v4.z, v4.w};
        #pragma unroll
        for (int k = 0; k < 4; ++k) {
            float v  = vs[k];
            float v2 = v * v;
            #pragma unroll
            for (int j = 0; j < NE; ++j) {
                float arg = fmaf(A[j], v2, fmaf(B[j], v, Cc[j]));
                acc[j] += __builtin_amdgcn_exp2f(arg);
            }
            float sarg = fmaf(sB, v, sC);
            float den  = 1.0f + __builtin_amdgcn_exp2f(sarg);
            acc[NE]   += __builtin_amdgcn_rcpf(den);
        }
    }

    // Wave (64-lane) butterfly reduce each accumulator.
    #pragma unroll
    for (int j = 0; j < NBINS; ++j) {
        float a = acc[j];
        #pragma unroll
        for (int off = 32; off > 0; off >>= 1)
            a += __shfl_down(a, off, 64);
        acc[j] = a;
    }

    // Cross-wave reduce via LDS (4 waves x 11 bins).
    __shared__ float red[4][NBINS];
    const int wave = tid >> 6;
    const int lane = tid & 63;
    if (lane == 0) {
        #pragma unroll
        for (int j = 0; j < NBINS; ++j) red[wave][j] = acc[j];
    }
    __syncthreads();
    if (tid < NBINS) {
        float s = red[0][tid] + red[1][tid] + red[2][tid] + red[3][tid];
        out[(size_t)bc * NBINS + tid] = s;
    }
}

extern "C" void kernel_launch(void* const* d_in, const int* in_sizes, int n_in,
                              void* d_out, int out_size, void* d_ws, size_t ws_size,
                              hipStream_t stream) {
    const float* x     = (const float*)d_in[0];
    const float* edges = (const float*)d_in[1];
    float* out         = (float*)d_out;
    // grid: 16 * 128 = 2048 blocks, one per (bt, c)
    hist_kernel<<<dim3(16 * NCH), dim3(256), 0, stream>>>(x, edges, out);
}